// Round 5
// baseline (311.895 us; speedup 1.0000x reference)
//
#include <hip/hip_runtime.h>
#include <hip/hip_bf16.h>

#define NUM_NODES 100000
#define BATCH 4096
#define NNB 64
#define HID 128
#define NHEAD 8
#define HDIM 16
#define TDIM 64
#define RDIM 64
#define START_TC 0.2f
#define END_TC 0.8f
#define NORMS 0.25f

typedef __attribute__((ext_vector_type(4))) float f32x4;
typedef __attribute__((ext_vector_type(8))) short bf16x8;

#define AST 136   // A-tile row stride in shorts (272B: 16B-aligned rows)
#define KST 130   // K tile row stride in shorts (260B: stride/4 % 32 == 1 -> 2-way max on row reads)
#define APAD 12   // attn_t row stride in floats (48B: 16B-aligned, 2-way max on f32x4 reads)

__device__ __forceinline__ short f2bs(float f) {
    unsigned u = __float_as_uint(f);
    u += 0x7fffu + ((u >> 16) & 1u);   // RNE
    return (short)(u >> 16);
}
__device__ __forceinline__ float bs2f(short s) {
    return __uint_as_float(((unsigned)(unsigned short)s) << 16);
}

// Pack weights into MFMA B-fragment order, combined biases, and q0 = t_q(START_T).
__global__ void prep_kernel(const float* __restrict__ t2v_w, const float* __restrict__ t2v_b,
                            const float* __restrict__ tW_k, const float* __restrict__ tb_k,
                            const float* __restrict__ tW_q, const float* __restrict__ tb_q,
                            const float* __restrict__ tW_v, const float* __restrict__ tb_v,
                            const float* __restrict__ rW_k, const float* __restrict__ rb_k,
                            const float* __restrict__ rW_v, const float* __restrict__ rb_v,
                            short* __restrict__ wfrag, float* __restrict__ bias_kv,
                            float* __restrict__ q0_add)
{
    int blk = blockIdx.x, t = threadIdx.x;
    if (blk < 128) {
        // wfrag[((kt*16+nt)*64 + lane)*8 + i] = W[kt*32 + (lane>>4)*8 + i][nt*16 + (lane&15)]
        int idx = blk * 256 + t;
        int i   = idx & 7;
        int ln  = (idx >> 3) & 63;
        int nt  = (idx >> 9) & 15;
        int kt  = idx >> 13;
        int k = kt * 32 + (ln >> 4) * 8 + i;
        int c = nt * 16 + (ln & 15);
        int cc = (c < HID) ? c : c - HID;
        float val;
        if (k < TDIM) val = (c < HID) ? tW_k[k*HID + cc] : tW_v[k*HID + cc];
        else          val = (c < HID) ? rW_k[(k-TDIM)*HID + cc] : rW_v[(k-TDIM)*HID + cc];
        wfrag[idx] = f2bs(val);
    } else if (blk == 128) {
        bias_kv[t] = (t < HID) ? (tb_k[t] + rb_k[t]) : (tb_v[t-HID] + rb_v[t-HID]);
    } else if (t < HID) {
        float s = tb_q[t];
        for (int j = 0; j < TDIM; ++j) {
            float f = START_TC * t2v_w[j] + t2v_b[j];
            float tv = (j == 0) ? f : __sinf(f);
            s += tv * tW_q[j*HID + t];
        }
        q0_add[t] = s;
    }
}

__launch_bounds__(256, 7)
__global__ void aggr_kernel(const float* __restrict__ k_tab, const float* __restrict__ q_tab,
                            const float* __restrict__ v_tab,
                            const int* __restrict__ nid, const int* __restrict__ neighbors,
                            const float* __restrict__ times, const float* __restrict__ rels,
                            const float* __restrict__ t2v_w, const float* __restrict__ t2v_b,
                            const short* __restrict__ wfrag, const float* __restrict__ bias_kv,
                            const float* __restrict__ q0_add, float* __restrict__ out)
{
    // A-tile (GEMM input) is dead after phase 2; Ksh reuses the same LDS.
    __shared__ __align__(16) short AK[64 * AST];
    __shared__ float q_lds[HID];
    __shared__ float maskadd[NNB];
    __shared__ int   nb_lds[NNB];
    __shared__ float attn_t[NNB][APAD];   // [n][head], padded
    __shared__ int   anyvalid;

    short* A   = AK;   // stride AST, phases 1-2
    short* Ksh = AK;   // stride KST, phases 3-4

    const int b = blockIdx.x;
    const int t = threadIdx.x;
    const int w = t >> 6;   // wave 0..3
    const int l = t & 63;   // lane

    // ---- phase 0: neighbors / times-mask / q (no barrier: consumers are all
    //      after the phase-1 barrier) ----
    if (t < 64) {
        nb_lds[t] = neighbors[b*NNB + t];
        float tt = times[b*NNB + t];
        bool valid = (tt >= START_TC) && (tt < END_TC);
        maskadd[t] = valid ? 0.f : -1e30f;
        unsigned long long bal = __ballot(valid);
        if (t == 0) anyvalid = (bal != 0ull) ? 1 : 0;
    } else if (t < 96) {
        int i = t - 64;                 // 0..31
        int q_node = nid[b];
        f32x4 qa = *(const f32x4*)(q_tab + (size_t)q_node*HID + i*4);
        f32x4 qb = *(const f32x4*)(q0_add + i*4);
        *(f32x4*)(q_lds + i*4) = qa + qb;
    }

    // ---- phase 1: stage A-tile = [t2v(times) | rels] as bf16 ----
    {
        int n  = t >> 2;
        int c0 = (t & 3) * 16;
        float tt = times[b*NNB + n];    // 4-lane broadcast read, avoids LDS dep
        bf16x8 v0, v1;
        #pragma unroll
        for (int u = 0; u < 8; ++u) {
            int j = c0 + u;
            float f = fmaf(tt, t2v_w[j], t2v_b[j]);
            v0[u] = f2bs((j == 0) ? f : __sinf(f));
        }
        #pragma unroll
        for (int u = 0; u < 8; ++u) {
            int j = c0 + 8 + u;
            float f = fmaf(tt, t2v_w[j], t2v_b[j]);
            v1[u] = f2bs(__sinf(f));
        }
        *(bf16x8*)(&A[n*AST + c0])     = v0;
        *(bf16x8*)(&A[n*AST + c0 + 8]) = v1;

        const float* rp = rels + ((size_t)b*NNB + n)*RDIM + c0;
        f32x4 r0 = *(const f32x4*)(rp);
        f32x4 r1 = *(const f32x4*)(rp + 4);
        f32x4 r2 = *(const f32x4*)(rp + 8);
        f32x4 r3 = *(const f32x4*)(rp + 12);
        bf16x8 o0, o1;
        #pragma unroll
        for (int e = 0; e < 4; ++e) {
            o0[e]   = f2bs(r0[e]);  o0[e+4] = f2bs(r1[e]);
            o1[e]   = f2bs(r2[e]);  o1[e+4] = f2bs(r3[e]);
        }
        *(bf16x8*)(&A[n*AST + TDIM + c0])     = o0;
        *(bf16x8*)(&A[n*AST + TDIM + c0 + 8]) = o1;
    }
    __syncthreads();

    // ---- phase 2: GEMM [64x128] @ [128x256] -> acc; wave w owns cols 64w..64w+63 ----
    f32x4 acc[4][4];
    #pragma unroll
    for (int mt = 0; mt < 4; ++mt)
        #pragma unroll
        for (int j = 0; j < 4; ++j)
            acc[mt][j] = (f32x4){0.f, 0.f, 0.f, 0.f};

    const bf16x8* wf = (const bf16x8*)wfrag;
    #pragma unroll
    for (int kt = 0; kt < 4; ++kt) {
        bf16x8 af[4], bfrag[4];
        int kcol = kt*32 + (l >> 4)*8;
        #pragma unroll
        for (int mt = 0; mt < 4; ++mt)
            af[mt] = *(const bf16x8*)(&A[(mt*16 + (l & 15))*AST + kcol]);
        #pragma unroll
        for (int j = 0; j < 4; ++j)
            bfrag[j] = wf[(kt*16 + (4*w + j))*64 + l];
        #pragma unroll
        for (int mt = 0; mt < 4; ++mt)
            #pragma unroll
            for (int j = 0; j < 4; ++j)
                acc[mt][j] = __builtin_amdgcn_mfma_f32_16x16x32_bf16(af[mt], bfrag[j], acc[mt][j], 0, 0, 0);
    }
    __syncthreads();   // A is dead; Ksh may now overwrite it

    // ---- phase 3: epilogue — gather table rows + bias.
    // waves 0,1: k -> bf16 Ksh (LDS). waves 2,3: v stays f32 in acc registers.
    if (w < 2) {
        float biasr[4];
        #pragma unroll
        for (int j = 0; j < 4; ++j)
            biasr[j] = bias_kv[((w & 1) << 6) + j*16 + (l & 15)];
        #pragma unroll
        for (int mt = 0; mt < 4; ++mt) {
            #pragma unroll
            for (int i = 0; i < 4; ++i) {
                int n = mt*16 + ((l >> 4) << 2) + i;
                const float* trow = k_tab + (size_t)nb_lds[n]*HID;
                #pragma unroll
                for (int j = 0; j < 4; ++j) {
                    int colT = ((w & 1) << 6) + j*16 + (l & 15);
                    Ksh[n*KST + colT] = f2bs(acc[mt][j][i] + biasr[j] + trow[colT]);
                }
            }
        }
    } else {
        float biasr[4];
        #pragma unroll
        for (int j = 0; j < 4; ++j)
            biasr[j] = bias_kv[HID + ((w & 1) << 6) + j*16 + (l & 15)];
        #pragma unroll
        for (int mt = 0; mt < 4; ++mt) {
            #pragma unroll
            for (int i = 0; i < 4; ++i) {
                int n = mt*16 + ((l >> 4) << 2) + i;
                const float* trow = v_tab + (size_t)nb_lds[n]*HID;
                #pragma unroll
                for (int j = 0; j < 4; ++j) {
                    int colT = ((w & 1) << 6) + j*16 + (l & 15);
                    acc[mt][j][i] += biasr[j] + trow[colT];
                }
            }
        }
    }
    __syncthreads();

    // ---- phase 4: scores + softmax. lane l owns neighbor n=l; wave w owns heads 2w,2w+1 ----
    {
        const short* krow = &Ksh[l*KST];
        float sc[2];
        #pragma unroll
        for (int hh = 0; hh < 2; ++hh) {
            int h = 2*w + hh;
            float s = 0.f;
            #pragma unroll
            for (int e = 0; e < 8; ++e) {
                unsigned u = *(const unsigned*)(&krow[h*16 + 2*e]);
                float k0 = __uint_as_float(u << 16);
                float k1 = __uint_as_float(u & 0xffff0000u);
                s = fmaf(q_lds[h*16 + 2*e],     k0, s);
                s = fmaf(q_lds[h*16 + 2*e + 1], k1, s);
            }
            sc[hh] = s * NORMS + maskadd[l];
        }
        #pragma unroll
        for (int hh = 0; hh < 2; ++hh) {
            float m = sc[hh];
            #pragma unroll
            for (int off = 1; off <= 32; off <<= 1)
                m = fmaxf(m, __shfl_xor(m, off));
            float e = __expf(sc[hh] - m);
            float sum = e;
            #pragma unroll
            for (int off = 1; off <= 32; off <<= 1)
                sum += __shfl_xor(sum, off);
            attn_t[l][2*w + hh] = e / sum;
        }
    }
    __syncthreads();

    // ---- phase 5: PV in registers (waves 2,3 hold v) + cross-group reduce ----
    if (w >= 2) {
        float p[4] = {0.f, 0.f, 0.f, 0.f};
        #pragma unroll
        for (int mt = 0; mt < 4; ++mt) {
            #pragma unroll
            for (int i = 0; i < 4; ++i) {
                int n = mt*16 + ((l >> 4) << 2) + i;
                f32x4 at = *(const f32x4*)(&attn_t[n][(w & 1) * 4]);
                #pragma unroll
                for (int j = 0; j < 4; ++j)
                    p[j] = fmaf(at[j], acc[mt][j][i], p[j]);
            }
        }
        #pragma unroll
        for (int j = 0; j < 4; ++j) {
            p[j] += __shfl_xor(p[j], 16);
            p[j] += __shfl_xor(p[j], 32);
        }
        if (l < 16) {
            #pragma unroll
            for (int j = 0; j < 4; ++j) {
                int col = ((w & 1) << 6) + j*16 + l;
                out[(size_t)b*HID + col] = anyvalid ? p[j] : 0.f;
            }
        }
    }
}

extern "C" void kernel_launch(void* const* d_in, const int* in_sizes, int n_in,
                              void* d_out, int out_size, void* d_ws, size_t ws_size,
                              hipStream_t stream)
{
    const float* k_tab = (const float*)d_in[0];
    const float* q_tab = (const float*)d_in[1];
    const float* v_tab = (const float*)d_in[2];
    const int*   nid   = (const int*)d_in[3];
    const int*   neighbors = (const int*)d_in[4];
    const float* times = (const float*)d_in[5];
    const float* rels  = (const float*)d_in[6];
    const float* t2v_w = (const float*)d_in[7];
    const float* t2v_b = (const float*)d_in[8];
    const float* tW_k  = (const float*)d_in[9];
    const float* tb_k  = (const float*)d_in[10];
    const float* tW_q  = (const float*)d_in[11];
    const float* tb_q  = (const float*)d_in[12];
    const float* tW_v  = (const float*)d_in[13];
    const float* tb_v  = (const float*)d_in[14];
    const float* rW_k  = (const float*)d_in[15];
    const float* rb_k  = (const float*)d_in[16];
    const float* rW_v  = (const float*)d_in[17];
    const float* rb_v  = (const float*)d_in[18];

    short* wfrag   = (short*)d_ws;                          // 32768 bf16 = 64KB
    float* bias_kv = (float*)((char*)d_ws + 65536);         // 256 f32
    float* q0_add  = (float*)((char*)d_ws + 65536 + 1024);  // 128 f32

    prep_kernel<<<130, 256, 0, stream>>>(t2v_w, t2v_b, tW_k, tb_k, tW_q, tb_q,
                                         tW_v, tb_v, rW_k, rb_k, rW_v, rb_v,
                                         wfrag, bias_kv, q0_add);
    aggr_kernel<<<BATCH, 256, 0, stream>>>(k_tab, q_tab, v_tab, nid, neighbors,
                                           times, rels, t2v_w, t2v_b,
                                           wfrag, bias_kv, q0_add, (float*)d_out);
}

// Round 6
// 63.645 us; speedup vs baseline: 4.9005x; 4.9005x over previous
//
#include <hip/hip_runtime.h>
#include <hip/hip_bf16.h>

#define NUM_NODES 100000
#define BATCH 4096
#define NNB 64
#define HID 128
#define NHEAD 8
#define HDIM 16
#define TDIM 64
#define RDIM 64
#define START_TC 0.2f
#define END_TC 0.8f
#define NORMS 0.25f

typedef __attribute__((ext_vector_type(4))) float f32x4;
typedef __attribute__((ext_vector_type(8))) short bf16x8;

#define AST 136   // A-tile row stride in shorts (272B: 16B-aligned rows)
#define KST 130   // K tile row stride in shorts (260B: stride/4 % 32 == 1 -> ~conflict-free row reads)
#define APAD 9    // attn_t row stride in floats (odd -> conflict-free scalar writes/reads)

__device__ __forceinline__ short f2bs(float f) {
    unsigned u = __float_as_uint(f);
    u += 0x7fffu + ((u >> 16) & 1u);   // RNE
    return (short)(u >> 16);
}

// Pack weights into MFMA B-fragment order, combined biases, and q0 = t_q(START_T).
__global__ void prep_kernel(const float* __restrict__ t2v_w, const float* __restrict__ t2v_b,
                            const float* __restrict__ tW_k, const float* __restrict__ tb_k,
                            const float* __restrict__ tW_q, const float* __restrict__ tb_q,
                            const float* __restrict__ tW_v, const float* __restrict__ tb_v,
                            const float* __restrict__ rW_k, const float* __restrict__ rb_k,
                            const float* __restrict__ rW_v, const float* __restrict__ rb_v,
                            short* __restrict__ wfrag, float* __restrict__ bias_kv,
                            float* __restrict__ q0_add)
{
    int blk = blockIdx.x, t = threadIdx.x;
    if (blk < 128) {
        // wfrag[((kt*16+nt)*64 + lane)*8 + i] = W[kt*32 + (lane>>4)*8 + i][nt*16 + (lane&15)]
        int idx = blk * 256 + t;
        int i   = idx & 7;
        int ln  = (idx >> 3) & 63;
        int nt  = (idx >> 9) & 15;
        int kt  = idx >> 13;
        int k = kt * 32 + (ln >> 4) * 8 + i;
        int c = nt * 16 + (ln & 15);
        int cc = (c < HID) ? c : c - HID;
        float val;
        if (k < TDIM) val = (c < HID) ? tW_k[k*HID + cc] : tW_v[k*HID + cc];
        else          val = (c < HID) ? rW_k[(k-TDIM)*HID + cc] : rW_v[(k-TDIM)*HID + cc];
        wfrag[idx] = f2bs(val);
    } else if (blk == 128) {
        bias_kv[t] = (t < HID) ? (tb_k[t] + rb_k[t]) : (tb_v[t-HID] + rb_v[t-HID]);
    } else if (t < HID) {
        float s = tb_q[t];
        for (int j = 0; j < TDIM; ++j) {
            float f = START_TC * t2v_w[j] + t2v_b[j];
            float tv = (j == 0) ? f : __sinf(f);
            s += tv * tW_q[j*HID + t];
        }
        q0_add[t] = s;
    }
}

// 512 threads = 8 waves. Wave w owns output cols 32w..32w+31 (acc[4][2] = 32 f32/lane).
// Reg budget: ~32 acc + ~48 working ~= 80/lane -> target 3 blocks/CU (24 waves, 75%).
__launch_bounds__(512, 6)
__global__ void aggr_kernel(const float* __restrict__ k_tab, const float* __restrict__ q_tab,
                            const float* __restrict__ v_tab,
                            const int* __restrict__ nid, const int* __restrict__ neighbors,
                            const float* __restrict__ times, const float* __restrict__ rels,
                            const float* __restrict__ t2v_w, const float* __restrict__ t2v_b,
                            const short* __restrict__ wfrag, const float* __restrict__ bias_kv,
                            const float* __restrict__ q0_add, float* __restrict__ out)
{
    // A-tile (GEMM input) is dead after phase 2; Ksh reuses the same LDS.
    __shared__ __align__(16) short AK[64 * AST];
    __shared__ float q_lds[HID];
    __shared__ float maskadd[NNB];
    __shared__ int   nb_lds[NNB];
    __shared__ float attn_t[NNB][APAD];   // [n][head]
    __shared__ int   anyvalid;

    short* A   = AK;   // stride AST, phases 1-2
    short* Ksh = AK;   // stride KST, phases 3-4

    const int b = blockIdx.x;
    const int t = threadIdx.x;
    const int w = t >> 6;   // wave 0..7
    const int l = t & 63;   // lane

    // ---- phase 0: neighbors / mask / q (consumers all after first barrier) ----
    if (t < 64) {
        nb_lds[t] = neighbors[b*NNB + t];
        float tt = times[b*NNB + t];
        bool valid = (tt >= START_TC) && (tt < END_TC);
        maskadd[t] = valid ? 0.f : -1e30f;
        unsigned long long bal = __ballot(valid);
        if (t == 0) anyvalid = (bal != 0ull) ? 1 : 0;
    } else if (t < 96) {
        int i = t - 64;                 // 0..31
        int q_node = nid[b];
        f32x4 qa = *(const f32x4*)(q_tab + (size_t)q_node*HID + i*4);
        f32x4 qb = *(const f32x4*)(q0_add + i*4);
        *(f32x4*)(q_lds + i*4) = qa + qb;
    }

    // ---- phase 1: stage A-tile = [t2v(times) | rels], wave-specialized ----
    if (w < 4) {
        // waves 0-3: t2v columns 16w..16w+15 for row l (pure VALU after one coalesced load)
        float tt = times[b*NNB + l];
        int c0 = w * 16;
        bf16x8 v0, v1;
        #pragma unroll
        for (int u = 0; u < 8; ++u) {
            int j = c0 + u;
            float f = fmaf(tt, t2v_w[j], t2v_b[j]);
            v0[u] = f2bs((j == 0) ? f : __sinf(f));
        }
        #pragma unroll
        for (int u = 0; u < 8; ++u) {
            int j = c0 + 8 + u;
            float f = fmaf(tt, t2v_w[j], t2v_b[j]);
            v1[u] = f2bs(__sinf(f));
        }
        *(bf16x8*)(&A[l*AST + c0])     = v0;
        *(bf16x8*)(&A[l*AST + c0 + 8]) = v1;
    } else {
        // waves 4-7: rels columns 16s..16s+15 for row l (pure loads)
        int s = w - 4;
        const float* rp = rels + ((size_t)b*NNB + l)*RDIM + s*16;
        f32x4 r0 = *(const f32x4*)(rp);
        f32x4 r1 = *(const f32x4*)(rp + 4);
        f32x4 r2 = *(const f32x4*)(rp + 8);
        f32x4 r3 = *(const f32x4*)(rp + 12);
        bf16x8 o0, o1;
        #pragma unroll
        for (int e = 0; e < 4; ++e) {
            o0[e]   = f2bs(r0[e]);  o0[e+4] = f2bs(r1[e]);
            o1[e]   = f2bs(r2[e]);  o1[e+4] = f2bs(r3[e]);
        }
        *(bf16x8*)(&A[l*AST + TDIM + s*16])     = o0;
        *(bf16x8*)(&A[l*AST + TDIM + s*16 + 8]) = o1;
    }
    __syncthreads();

    // ---- phase 2: GEMM [64x128] @ [128x256]; wave w owns cols 32w..32w+31 ----
    f32x4 acc[4][2];
    #pragma unroll
    for (int mt = 0; mt < 4; ++mt)
        #pragma unroll
        for (int j = 0; j < 2; ++j)
            acc[mt][j] = (f32x4){0.f, 0.f, 0.f, 0.f};

    const bf16x8* wf = (const bf16x8*)wfrag;
    #pragma unroll
    for (int kt = 0; kt < 4; ++kt) {
        bf16x8 af[4], bfrag[2];
        int kcol = kt*32 + (l >> 4)*8;
        #pragma unroll
        for (int mt = 0; mt < 4; ++mt)
            af[mt] = *(const bf16x8*)(&A[(mt*16 + (l & 15))*AST + kcol]);
        #pragma unroll
        for (int j = 0; j < 2; ++j)
            bfrag[j] = wf[(kt*16 + (2*w + j))*64 + l];
        #pragma unroll
        for (int mt = 0; mt < 4; ++mt)
            #pragma unroll
            for (int j = 0; j < 2; ++j)
                acc[mt][j] = __builtin_amdgcn_mfma_f32_16x16x32_bf16(af[mt], bfrag[j], acc[mt][j], 0, 0, 0);
    }
    __syncthreads();   // A is dead; Ksh may now overwrite it

    // ---- phase 3: gather table rows + bias.
    // waves 0-3: k -> bf16 Ksh (LDS). waves 4-7: v stays f32 in acc registers.
    if (w < 4) {
        int cw = w * 32;
        float biasr[2];
        #pragma unroll
        for (int j = 0; j < 2; ++j)
            biasr[j] = bias_kv[cw + j*16 + (l & 15)];
        #pragma unroll
        for (int mt = 0; mt < 4; ++mt) {
            #pragma unroll
            for (int i = 0; i < 4; ++i) {
                int n = mt*16 + ((l >> 4) << 2) + i;
                const float* trow = k_tab + (size_t)nb_lds[n]*HID;
                #pragma unroll
                for (int j = 0; j < 2; ++j) {
                    int col = cw + j*16 + (l & 15);
                    Ksh[n*KST + col] = f2bs(acc[mt][j][i] + biasr[j] + trow[col]);
                }
            }
        }
    } else {
        int cw = (w - 4) * 32;
        float biasr[2];
        #pragma unroll
        for (int j = 0; j < 2; ++j)
            biasr[j] = bias_kv[HID + cw + j*16 + (l & 15)];
        #pragma unroll
        for (int mt = 0; mt < 4; ++mt) {
            #pragma unroll
            for (int i = 0; i < 4; ++i) {
                int n = mt*16 + ((l >> 4) << 2) + i;
                const float* trow = v_tab + (size_t)nb_lds[n]*HID;
                #pragma unroll
                for (int j = 0; j < 2; ++j)
                    acc[mt][j][i] += biasr[j] + trow[cw + j*16 + (l & 15)];
            }
        }
    }
    __syncthreads();

    // ---- phase 4: scores + softmax. lane l = neighbor l; wave w = head w ----
    {
        const short* krow = &Ksh[l*KST + w*16];
        float s = 0.f;
        #pragma unroll
        for (int e = 0; e < 8; ++e) {
            unsigned u = *(const unsigned*)(&krow[2*e]);
            float k0 = __uint_as_float(u << 16);
            float k1 = __uint_as_float(u & 0xffff0000u);
            s = fmaf(q_lds[w*16 + 2*e],     k0, s);
            s = fmaf(q_lds[w*16 + 2*e + 1], k1, s);
        }
        float sc = s * NORMS + maskadd[l];
        float m = sc;
        #pragma unroll
        for (int off = 1; off <= 32; off <<= 1)
            m = fmaxf(m, __shfl_xor(m, off));
        float e = __expf(sc - m);
        float sum = e;
        #pragma unroll
        for (int off = 1; off <= 32; off <<= 1)
            sum += __shfl_xor(sum, off);
        attn_t[l][w] = e / sum;
    }
    __syncthreads();

    // ---- phase 5: PV in registers (waves 4-7 hold v) + cross-group reduce ----
    if (w >= 4) {
        int g = w - 4;
        float p[2] = {0.f, 0.f};
        #pragma unroll
        for (int mt = 0; mt < 4; ++mt) {
            #pragma unroll
            for (int i = 0; i < 4; ++i) {
                int n = mt*16 + ((l >> 4) << 2) + i;
                #pragma unroll
                for (int j = 0; j < 2; ++j)
                    p[j] = fmaf(attn_t[n][2*g + j], acc[mt][j][i], p[j]);
            }
        }
        #pragma unroll
        for (int j = 0; j < 2; ++j) {
            p[j] += __shfl_xor(p[j], 16);
            p[j] += __shfl_xor(p[j], 32);
        }
        if (l < 16) {
            #pragma unroll
            for (int j = 0; j < 2; ++j) {
                int col = g*32 + j*16 + l;
                out[(size_t)b*HID + col] = anyvalid ? p[j] : 0.f;
            }
        }
    }
}

extern "C" void kernel_launch(void* const* d_in, const int* in_sizes, int n_in,
                              void* d_out, int out_size, void* d_ws, size_t ws_size,
                              hipStream_t stream)
{
    const float* k_tab = (const float*)d_in[0];
    const float* q_tab = (const float*)d_in[1];
    const float* v_tab = (const float*)d_in[2];
    const int*   nid   = (const int*)d_in[3];
    const int*   neighbors = (const int*)d_in[4];
    const float* times = (const float*)d_in[5];
    const float* rels  = (const float*)d_in[6];
    const float* t2v_w = (const float*)d_in[7];
    const float* t2v_b = (const float*)d_in[8];
    const float* tW_k  = (const float*)d_in[9];
    const float* tb_k  = (const float*)d_in[10];
    const float* tW_q  = (const float*)d_in[11];
    const float* tb_q  = (const float*)d_in[12];
    const float* tW_v  = (const float*)d_in[13];
    const float* tb_v  = (const float*)d_in[14];
    const float* rW_k  = (const float*)d_in[15];
    const float* rb_k  = (const float*)d_in[16];
    const float* rW_v  = (const float*)d_in[17];
    const float* rb_v  = (const float*)d_in[18];

    short* wfrag   = (short*)d_ws;                          // 32768 bf16 = 64KB
    float* bias_kv = (float*)((char*)d_ws + 65536);         // 256 f32
    float* q0_add  = (float*)((char*)d_ws + 65536 + 1024);  // 128 f32

    prep_kernel<<<130, 256, 0, stream>>>(t2v_w, t2v_b, tW_k, tb_k, tW_q, tb_q,
                                         tW_v, tb_v, rW_k, rb_k, rW_v, rb_v,
                                         wfrag, bias_kv, q0_add);
    aggr_kernel<<<BATCH, 512, 0, stream>>>(k_tab, q_tab, v_tab, nid, neighbors,
                                           times, rels, t2v_w, t2v_b,
                                           wfrag, bias_kv, q0_add, (float*)d_out);
}